// Round 5
// baseline (4805.652 us; speedup 1.0000x reference)
//
#include <hip/hip_runtime.h>
#include <hip/hip_bf16.h>

#define BB 8
#define NN 2048
#define KK 20

typedef __hip_bfloat16 bf16;
typedef unsigned short u16;

__device__ __forceinline__ float b2f(bf16 v) { return __bfloat162float(v); }

// ---------------------------------------------------------------- sq = sum(x*x)
template<int C>
__global__ __launch_bounds__(256) void sq_kernel(const float* __restrict__ xin,
                                                 float* __restrict__ sq) {
    int t = blockIdx.x * 256 + threadIdx.x;
    if (t >= BB * NN) return;
    float s = 0.f;
    const float* p = xin + (size_t)t * C;
    for (int c = 0; c < C; ++c) { float v = p[c]; s += v * v; }
    sq[t] = s;
}

// ---------------------------------------------------------------- kNN (top-K smallest dist)
// One block per point i; 20 rounds of lexicographic (val,idx) argmin reproduce
// jax.lax.top_k's lowest-index-first tie-break. Indices stored u16 (N=2048).
template<int C>
__global__ __launch_bounds__(256) void knn_kernel(const float* __restrict__ xin,
                                                  const float* __restrict__ sq,
                                                  u16* __restrict__ idx_out) {
    const int bn = blockIdx.x;
    const int b = bn >> 11;
    const int tid = threadIdx.x;
    __shared__ float dist[NN];
    __shared__ float xi[C];
    __shared__ float sval[256];
    __shared__ int   sidx[256];

    if (tid < C) xi[tid] = xin[(size_t)bn * C + tid];
    __syncthreads();
    const float sqi = sq[bn];
    for (int j = tid; j < NN; j += 256) {
        const float* xj = xin + ((size_t)(b * NN + j)) * C;
        float dot = 0.f;
        for (int c = 0; c < C; ++c) dot += xi[c] * xj[c];
        dist[j] = (sqi + sq[b * NN + j]) - 2.f * dot;
    }
    __syncthreads();

    for (int k = 0; k < KK; ++k) {
        float bv = INFINITY; int bi = 0x7fffffff;
        for (int j = tid; j < NN; j += 256) {
            float v = dist[j];
            if (v < bv) { bv = v; bi = j; }   // strict-less keeps lowest index on ties
        }
        sval[tid] = bv; sidx[tid] = bi;
        __syncthreads();
        if (tid < 64) {
            float v0 = sval[tid]; int i0 = sidx[tid];
            #pragma unroll
            for (int u = 1; u < 4; ++u) {
                float v = sval[tid + 64 * u]; int ii = sidx[tid + 64 * u];
                if (v < v0 || (v == v0 && ii < i0)) { v0 = v; i0 = ii; }
            }
            #pragma unroll
            for (int off = 32; off; off >>= 1) {
                float v = __shfl_down(v0, off); int ii = __shfl_down(i0, off);
                if (v < v0 || (v == v0 && ii < i0)) { v0 = v; i0 = ii; }
            }
            if (tid == 0) {
                int safe = (i0 < NN) ? i0 : 0;
                idx_out[bn * KK + k] = (u16)safe;
                dist[safe] = INFINITY;
            }
        }
        __syncthreads();
    }
}

// ---------------------------------------------------------------- EdgeConv MLP + max over K
// Weights arrive fp32; staged to LDS as bf16 (keeps ec2 LDS at 24 KB).
template<int CIN, int COUT, bool BF16OUT>
__global__ __launch_bounds__(COUT) void edgeconv_kernel(
        const float* __restrict__ xin, const u16* __restrict__ knn,
        const float* __restrict__ w1, const float* __restrict__ b1,
        const float* __restrict__ w2, const float* __restrict__ b2,
        void* __restrict__ out) {
    const int bn = blockIdx.x;
    const int b = bn >> 11;
    const int tid = threadIdx.x;   // blockDim == COUT (>= 64, >= CIN)
    __shared__ bf16 w1s[2 * CIN * 64];
    __shared__ bf16 w2s[64 * COUT];
    __shared__ float b1s[64], b2s[COUT], xi[CIN], e[2 * CIN], h1[64];

    for (int p = tid; p < 2 * CIN * 64; p += COUT) w1s[p] = __float2bfloat16(w1[p]);
    for (int p = tid; p < 64 * COUT; p += COUT)    w2s[p] = __float2bfloat16(w2[p]);
    if (tid < 64) b1s[tid] = b1[tid];
    b2s[tid] = b2[tid];
    if (tid < CIN) xi[tid] = xin[(size_t)bn * CIN + tid];
    __syncthreads();

    float accmax = -INFINITY;
    for (int k = 0; k < KK; ++k) {
        int j = knn[bn * KK + k];
        if (j >= NN) j = 0;   // safety clamp
        if (tid < CIN) {
            float xj = xin[((size_t)(b * NN + j)) * CIN + tid];
            e[tid] = xi[tid];
            e[CIN + tid] = xj - xi[tid];
        }
        __syncthreads();
        if (tid < 64) {
            float v = 0.f;
            for (int c = 0; c < 2 * CIN; ++c) v += e[c] * b2f(w1s[c * 64 + tid]);
            h1[tid] = fmaxf(v + b1s[tid], 0.f);
        }
        __syncthreads();
        {
            float v = 0.f;
            for (int c = 0; c < 64; ++c) v += h1[c] * b2f(w2s[c * COUT + tid]);
            accmax = fmaxf(accmax, v + b2s[tid]);
        }
        __syncthreads();
    }
    if (BF16OUT) ((bf16*)out)[(size_t)bn * COUT + tid] = __float2bfloat16(accmax);
    else         ((float*)out)[(size_t)bn * COUT + tid] = accmax;
}

// ---------------------------------------------------------------- global max over N (2-stage)
__global__ __launch_bounds__(128) void gmax1_kernel(const bf16* __restrict__ f2,
                                                    float* __restrict__ pmax) {
    const int b = blockIdx.x >> 4, ch = blockIdx.x & 15, c = threadIdx.x;
    float m = -INFINITY;
    const bf16* base = f2 + ((size_t)(b * NN + ch * 128)) * 128 + c;
    for (int n = 0; n < 128; ++n) m = fmaxf(m, b2f(base[(size_t)n * 128]));
    pmax[blockIdx.x * 128 + c] = m;
}

__global__ __launch_bounds__(128) void gmax2_kernel(const float* __restrict__ pmax,
                                                    float* __restrict__ glob) {
    const int b = blockIdx.x, c = threadIdx.x;
    float m = -INFINITY;
    for (int ch = 0; ch < 16; ++ch) m = fmaxf(m, pmax[(b * 16 + ch) * 128 + c]);
    glob[b * 128 + c] = m;
}

// ---------------------------------------------------------------- K_h, V_h for one head (4 rows/block)
__global__ __launch_bounds__(256) void kvh_kernel(const bf16* __restrict__ f2,
                                                  const float* __restrict__ qkv_w,
                                                  bf16* __restrict__ kk,
                                                  bf16* __restrict__ vv, int h) {
    const int bn0 = blockIdx.x * 4;
    const int tid = threadIdx.x;
    __shared__ float Ws[2][128][32];  // 32 KB: [K|V][c][d] for head h
    __shared__ float f2s[4][128];
    for (int p = tid; p < 2 * 128 * 32; p += 256) {
        int kv = p >> 12, c = (p >> 5) & 127, d = p & 31;
        Ws[kv][c][d] = qkv_w[c * 384 + 128 + kv * 128 + h * 32 + d];
    }
    for (int p = tid; p < 4 * 128; p += 256) {
        int rr = p >> 7, c = p & 127;
        f2s[rr][c] = b2f(f2[(size_t)(bn0 + rr) * 128 + c]);
    }
    __syncthreads();
    const int rr = tid >> 6, u = tid & 63, kv = u >> 5, d = u & 31;
    float acc = 0.f;
    for (int c = 0; c < 128; ++c) acc += f2s[rr][c] * Ws[kv][c][d];
    bf16* dst = kv ? vv : kk;
    dst[(size_t)(bn0 + rr) * 32 + d] = __float2bfloat16(acc);
}

// ---------------------------------------------------------------- attention, one head (exact 2-pass softmax)
// Block = (b, tile of 64 q-rows); thread = (row r, j-split sp of 512).
__global__ __launch_bounds__(256) void attnh_kernel(const bf16* __restrict__ f2,
                                                    const float* __restrict__ qkv_w,
                                                    const bf16* __restrict__ kk,
                                                    const bf16* __restrict__ vv,
                                                    bf16* __restrict__ atth, int h) {
    const int blk = blockIdx.x;            // B*32 = 256
    const int tile = blk & 31;
    const int b = blk >> 5;
    const int tid = threadIdx.x;
    const int r = tid & 63;
    const int sp = tid >> 6;
    const int i = tile * 64 + r;
    const float scale = 0.17677669529663687f;  // 32^-0.5
    __shared__ float WqS[128 * 32];        // 16 KB
    __shared__ float mred[4][64], lred[4][64];
    __shared__ float accs[4][64][32];      // 32 KB

    for (int p = tid; p < 4096; p += 256) {
        int c = p >> 5, d = p & 31;
        WqS[p] = qkv_w[c * 384 + h * 32 + d];
    }
    __syncthreads();

    // q = f2_row @ Wq_h  (scalar loads; each of the 4 split-threads recomputes)
    float q[32];
    #pragma unroll
    for (int d = 0; d < 32; ++d) q[d] = 0.f;
    const bf16* frow = f2 + (size_t)(b * NN + i) * 128;
    for (int c = 0; c < 128; ++c) {
        float fv = b2f(frow[c]);
        const float* wrow = &WqS[c * 32];
        #pragma unroll
        for (int d = 0; d < 32; ++d) q[d] += fv * wrow[d];
    }

    const bf16* kb = kk + (size_t)b * NN * 32;
    const bf16* vb = vv + (size_t)b * NN * 32;
    const int j0 = sp * 512, j1 = j0 + 512;

    // pass A: row max over this split
    float m = -INFINITY;
    for (int j = j0; j < j1; ++j) {
        const bf16* kr = kb + (size_t)j * 32;
        float dsum = 0.f;
        #pragma unroll
        for (int d = 0; d < 32; ++d) dsum += q[d] * b2f(kr[d]);
        m = fmaxf(m, dsum * scale);
    }
    mred[sp][r] = m;
    __syncthreads();
    m = fmaxf(fmaxf(mred[0][r], mred[1][r]), fmaxf(mred[2][r], mred[3][r]));

    // pass B: exp + PV accumulate
    float l = 0.f;
    float a[32];
    #pragma unroll
    for (int d = 0; d < 32; ++d) a[d] = 0.f;
    for (int j = j0; j < j1; ++j) {
        const bf16* kr = kb + (size_t)j * 32;
        float dsum = 0.f;
        #pragma unroll
        for (int d = 0; d < 32; ++d) dsum += q[d] * b2f(kr[d]);
        float p = expf(dsum * scale - m);
        l += p;
        const bf16* vr = vb + (size_t)j * 32;
        #pragma unroll
        for (int d = 0; d < 32; ++d) a[d] += p * b2f(vr[d]);
    }
    lred[sp][r] = l;
    #pragma unroll
    for (int d = 0; d < 32; ++d) accs[sp][r][d] = a[d];
    __syncthreads();

    // merge 4 splits, write columns [h*32, h*32+32) of atth[B,N,128]
    const int row = tid >> 2;
    const int dbase = (tid & 3) * 8;
    const float denom = lred[0][row] + lred[1][row] + lred[2][row] + lred[3][row];
    bf16* orow = atth + (size_t)(b * NN + tile * 64 + row) * 128 + h * 32;
    #pragma unroll
    for (int uu = 0; uu < 8; ++uu) {
        int d = dbase + uu;
        float v = accs[0][row][d] + accs[1][row][d] + accs[2][row][d] + accs[3][row][d];
        orow[d] = __float2bfloat16(v / denom);
    }
}

// ---------------------------------------------------------------- fused out-proj + concat + refine MLP + log_softmax
__global__ __launch_bounds__(128) void final_kernel(
        const bf16* __restrict__ f2, const float* __restrict__ glob,
        const bf16* __restrict__ atth,
        const float* __restrict__ out_w, const float* __restrict__ out_b,
        const float* __restrict__ r1_w, const float* __restrict__ r1_b,
        const float* __restrict__ r2_w, const float* __restrict__ r2_b,
        const float* __restrict__ r3_w, const float* __restrict__ r3_b,
        float* __restrict__ out) {
    const int bn0 = blockIdx.x * 4;
    const int b = bn0 >> 11;
    const int tid = threadIdx.x;
    __shared__ float attin[4][128], comb[4][384], h1[4][128], h2[4][64];
    __shared__ float logits[4][20], lse[4];

    #pragma unroll
    for (int rr = 0; rr < 4; ++rr) {
        attin[rr][tid]      = b2f(atth[(size_t)(bn0 + rr) * 128 + tid]);
        comb[rr][tid]       = b2f(f2[(size_t)(bn0 + rr) * 128 + tid]);
        comb[rr][128 + tid] = glob[b * 128 + tid];
    }
    __syncthreads();
    {   // attention output projection
        float a0 = 0.f, a1 = 0.f, a2 = 0.f, a3 = 0.f;
        for (int c = 0; c < 128; ++c) {
            float wv = out_w[c * 128 + tid];
            a0 += attin[0][c] * wv; a1 += attin[1][c] * wv;
            a2 += attin[2][c] * wv; a3 += attin[3][c] * wv;
        }
        float bb = out_b[tid];
        comb[0][256 + tid] = a0 + bb; comb[1][256 + tid] = a1 + bb;
        comb[2][256 + tid] = a2 + bb; comb[3][256 + tid] = a3 + bb;
    }
    __syncthreads();
    {   // r1: 384 -> 128, relu
        float a0 = 0.f, a1 = 0.f, a2 = 0.f, a3 = 0.f;
        for (int c = 0; c < 384; ++c) {
            float wv = r1_w[c * 128 + tid];
            a0 += comb[0][c] * wv; a1 += comb[1][c] * wv;
            a2 += comb[2][c] * wv; a3 += comb[3][c] * wv;
        }
        float bb = r1_b[tid];
        h1[0][tid] = fmaxf(a0 + bb, 0.f); h1[1][tid] = fmaxf(a1 + bb, 0.f);
        h1[2][tid] = fmaxf(a2 + bb, 0.f); h1[3][tid] = fmaxf(a3 + bb, 0.f);
    }
    __syncthreads();
    if (tid < 64) {   // r2: 128 -> 64, relu
        float a0 = 0.f, a1 = 0.f, a2 = 0.f, a3 = 0.f;
        for (int c = 0; c < 128; ++c) {
            float wv = r2_w[c * 64 + tid];
            a0 += h1[0][c] * wv; a1 += h1[1][c] * wv;
            a2 += h1[2][c] * wv; a3 += h1[3][c] * wv;
        }
        float bb = r2_b[tid];
        h2[0][tid] = fmaxf(a0 + bb, 0.f); h2[1][tid] = fmaxf(a1 + bb, 0.f);
        h2[2][tid] = fmaxf(a2 + bb, 0.f); h2[3][tid] = fmaxf(a3 + bb, 0.f);
    }
    __syncthreads();
    if (tid < 20) {   // r3: 64 -> 20
        float a0 = 0.f, a1 = 0.f, a2 = 0.f, a3 = 0.f;
        for (int c = 0; c < 64; ++c) {
            float wv = r3_w[c * 20 + tid];
            a0 += h2[0][c] * wv; a1 += h2[1][c] * wv;
            a2 += h2[2][c] * wv; a3 += h2[3][c] * wv;
        }
        float bb = r3_b[tid];
        logits[0][tid] = a0 + bb; logits[1][tid] = a1 + bb;
        logits[2][tid] = a2 + bb; logits[3][tid] = a3 + bb;
    }
    __syncthreads();
    if (tid < 4) {
        float m = -INFINITY;
        for (int u = 0; u < 20; ++u) m = fmaxf(m, logits[tid][u]);
        float s = 0.f;
        for (int u = 0; u < 20; ++u) s += expf(logits[tid][u] - m);
        lse[tid] = m + logf(s);
    }
    __syncthreads();
    if (tid < 80) {
        int rr = tid / 20, cls = tid % 20;
        out[(size_t)(bn0 + rr) * 20 + cls] = logits[rr][cls] - lse[rr];
    }
}

// ----------------------------------------------------------------------------
// All float inputs/outputs are fp32 (per the reference's dtypes).
// Workspace layout — 10,555,392 B total (proven to fit in rounds 3-4):
//   [0,        4 MB)  f2 (bf16, persists)
//   [4 MB,    10 MB)  shared slot:
//     phase 1-2:  sqb fp32 @4M (64 KB) | f1 fp32 @4M+64K (4 MB) |
//                 knn u16 @8M+64K (640 KB)
//     phase 4:    kk bf16 @4M (1 MB) | vv bf16 @5M (1 MB) | atth bf16 @6M (4 MB)
//   [10 MB, +68 KB)   pmax fp32 | glob fp32
extern "C" void kernel_launch(void* const* d_in, const int* in_sizes, int n_in,
                              void* d_out, int out_size, void* d_ws, size_t ws_size,
                              hipStream_t stream) {
    const float* x      = (const float*)d_in[0];
    const float* ec1_w1 = (const float*)d_in[2];
    const float* ec1_b1 = (const float*)d_in[3];
    const float* ec1_w2 = (const float*)d_in[4];
    const float* ec1_b2 = (const float*)d_in[5];
    const float* ec2_w1 = (const float*)d_in[6];
    const float* ec2_b1 = (const float*)d_in[7];
    const float* ec2_w2 = (const float*)d_in[8];
    const float* ec2_b2 = (const float*)d_in[9];
    const float* qkv_w  = (const float*)d_in[10];
    const float* out_w  = (const float*)d_in[11];
    const float* out_b  = (const float*)d_in[12];
    const float* r1_w   = (const float*)d_in[13];
    const float* r1_b   = (const float*)d_in[14];
    const float* r2_w   = (const float*)d_in[15];
    const float* r2_b   = (const float*)d_in[16];
    const float* r3_w   = (const float*)d_in[17];
    const float* r3_b   = (const float*)d_in[18];
    float* out = (float*)d_out;

    const size_t NEED = 10555392;
    if (ws_size < NEED) return;   // guard: clean numeric fail instead of GPU fault

    char* base = (char*)d_ws;
    const size_t MB = 1024 * 1024;
    bf16*  f2   = (bf16*)(base);
    float* sqb  = (float*)(base + 4 * MB);
    float* f1   = (float*)(base + 4 * MB + 65536);
    u16*   knn  = (u16*)(base + 8 * MB + 65536);   // dead before phase 4 reuse
    bf16*  kk   = (bf16*)(base + 4 * MB);          // phase-4 slot reuse
    bf16*  vv   = (bf16*)(base + 5 * MB);
    bf16*  atth = (bf16*)(base + 6 * MB);
    float* pmax = (float*)(base + 10 * MB);
    float* glob = (float*)(base + 10 * MB + 65536);

    sq_kernel<3><<<BB * NN / 256, 256, 0, stream>>>(x, sqb);
    knn_kernel<3><<<BB * NN, 256, 0, stream>>>(x, sqb, knn);
    edgeconv_kernel<3, 64, false><<<BB * NN, 64, 0, stream>>>(
        x, knn, ec1_w1, ec1_b1, ec1_w2, ec1_b2, f1);

    sq_kernel<64><<<BB * NN / 256, 256, 0, stream>>>(f1, sqb);
    knn_kernel<64><<<BB * NN, 256, 0, stream>>>(f1, sqb, knn);
    edgeconv_kernel<64, 128, true><<<BB * NN, 128, 0, stream>>>(
        f1, knn, ec2_w1, ec2_b1, ec2_w2, ec2_b2, f2);

    gmax1_kernel<<<BB * 16, 128, 0, stream>>>(f2, pmax);
    gmax2_kernel<<<BB, 128, 0, stream>>>(pmax, glob);

    for (int h = 0; h < 4; ++h) {
        kvh_kernel<<<BB * NN / 4, 256, 0, stream>>>(f2, qkv_w, kk, vv, h);
        attnh_kernel<<<BB * 32, 256, 0, stream>>>(f2, qkv_w, kk, vv, atth, h);
    }

    final_kernel<<<BB * NN / 4, 128, 0, stream>>>(
        f2, glob, atth, out_w, out_b, r1_w, r1_b, r2_w, r2_b, r3_w, r3_b, out);
}

// Round 6
// 3999.181 us; speedup vs baseline: 1.2017x; 1.2017x over previous
//
#include <hip/hip_runtime.h>
#include <hip/hip_bf16.h>

#define BB 8
#define NN 2048
#define KK 20
#define BBNN (BB * NN)

typedef __hip_bfloat16 bf16;
typedef unsigned short u16;

__device__ __forceinline__ float b2f(bf16 v) { return __bfloat162float(v); }

// ---------------------------------------------------------------- sq + transpose (fused)
// sq[t] = sum_c x[t][c]^2 (same c-order as before); xT[c][t] = x[t][c]
template<int C>
__global__ __launch_bounds__(256) void sqT_kernel(const float* __restrict__ xin,
                                                  float* __restrict__ sq,
                                                  float* __restrict__ xT) {
    int t = blockIdx.x * 256 + threadIdx.x;
    if (t >= BBNN) return;
    const float* p = xin + (size_t)t * C;
    float s = 0.f;
    for (int c = 0; c < C; ++c) {
        float v = p[c];
        s += v * v;
        xT[(size_t)c * BBNN + t] = v;
    }
    sq[t] = s;
}

// ---------------------------------------------------------------- fast kNN
// One block = 8 queries; one WAVE per query (no __syncthreads at all).
// dist[8][2048] fp32 = exactly 64 KB LDS. Phase A: lane s computes j = jj*64+s
// with coalesced reads from xT and wave-uniform (scalar-reg) query row; dot in
// identical c-ascending fp32 order as the passing round-5 kernel -> bit-exact
// distances -> identical neighbor sets. Phase B: per-lane chunk argmin cached
// in registers; per round a 6-step shfl_xor lexicographic (d,j) reduce; only
// the winner lane rescans its 32-element chunk after marking INF.
template<int C>
__global__ __launch_bounds__(512, 1) void knn_fast_kernel(
        const float* __restrict__ xrows,   // [BBNN][C] row-major (query reads)
        const float* __restrict__ xT,      // [C][BBNN] transposed (neighbor reads)
        const float* __restrict__ sq,
        u16* __restrict__ idx_out) {
    __shared__ float dist[8][2048];
    const int blk = blockIdx.x;            // BB * 256
    const int b = blk >> 8;
    const int tile = blk & 255;
    const int w = __builtin_amdgcn_readfirstlane((int)(threadIdx.x >> 6));
    const int s = threadIdx.x & 63;
    const int i = tile * 8 + w;            // query index within batch
    const int bn0 = b * NN;

    // query row -> registers (wave-uniform address -> scalar loads)
    const int qbase = __builtin_amdgcn_readfirstlane((bn0 + i) * C);
    float xq[C];
    #pragma unroll
    for (int c = 0; c < C; ++c) xq[c] = xrows[qbase + c];
    const float sqi = sq[bn0 + i];

    // ---- phase A: all 2048 distances for this query
    for (int jj = 0; jj < 32; ++jj) {
        int j = jj * 64 + s;
        float dot = 0.f;
        #pragma unroll
        for (int c = 0; c < C; ++c) dot += xq[c] * xT[(size_t)c * BBNN + bn0 + j];
        dist[w][j] = (sqi + sq[bn0 + j]) - 2.f * dot;   // same expr order as before
    }

    // ---- phase B: 20 rounds of lexicographic (d, j) argmin
    // lane s owns groups g = u*64+s (u=0..7), i.e. j in {4g..4g+3}
    float ld = INFINITY; int lj = 0x7fffffff;
    #pragma unroll
    for (int u = 0; u < 8; ++u) {
        int j0 = (u * 64 + s) * 4;
        float4 dv = *(const float4*)&dist[w][j0];
        if (dv.x < ld) { ld = dv.x; lj = j0; }
        if (dv.y < ld) { ld = dv.y; lj = j0 + 1; }
        if (dv.z < ld) { ld = dv.z; lj = j0 + 2; }
        if (dv.w < ld) { ld = dv.w; lj = j0 + 3; }
    }
    for (int r = 0; r < KK; ++r) {
        float rd = ld; int rj = lj;
        #pragma unroll
        for (int m = 1; m < 64; m <<= 1) {
            float od = __shfl_xor(rd, m);
            int   oj = __shfl_xor(rj, m);
            if (od < rd || (od == rd && oj < rj)) { rd = od; rj = oj; }
        }
        if (s == 0) idx_out[(size_t)(bn0 + i) * KK + r] = (u16)rj;
        if (r + 1 < KK) {
            int owner = (rj >> 2) & 63;
            if (s == owner) {
                dist[w][rj] = INFINITY;
                ld = INFINITY; lj = 0x7fffffff;
                #pragma unroll
                for (int u = 0; u < 8; ++u) {
                    int j0 = (u * 64 + s) * 4;
                    float4 dv = *(const float4*)&dist[w][j0];
                    if (dv.x < ld) { ld = dv.x; lj = j0; }
                    if (dv.y < ld) { ld = dv.y; lj = j0 + 1; }
                    if (dv.z < ld) { ld = dv.z; lj = j0 + 2; }
                    if (dv.w < ld) { ld = dv.w; lj = j0 + 3; }
                }
            }
        }
    }
}

// ---------------------------------------------------------------- EdgeConv MLP + max over K
template<int CIN, int COUT, bool BF16OUT>
__global__ __launch_bounds__(COUT) void edgeconv_kernel(
        const float* __restrict__ xin, const u16* __restrict__ knn,
        const float* __restrict__ w1, const float* __restrict__ b1,
        const float* __restrict__ w2, const float* __restrict__ b2,
        void* __restrict__ out) {
    const int bn = blockIdx.x;
    const int b = bn >> 11;
    const int tid = threadIdx.x;   // blockDim == COUT (>= 64, >= CIN)
    __shared__ bf16 w1s[2 * CIN * 64];
    __shared__ bf16 w2s[64 * COUT];
    __shared__ float b1s[64], b2s[COUT], xi[CIN], e[2 * CIN], h1[64];

    for (int p = tid; p < 2 * CIN * 64; p += COUT) w1s[p] = __float2bfloat16(w1[p]);
    for (int p = tid; p < 64 * COUT; p += COUT)    w2s[p] = __float2bfloat16(w2[p]);
    if (tid < 64) b1s[tid] = b1[tid];
    b2s[tid] = b2[tid];
    if (tid < CIN) xi[tid] = xin[(size_t)bn * CIN + tid];
    __syncthreads();

    float accmax = -INFINITY;
    for (int k = 0; k < KK; ++k) {
        int j = knn[bn * KK + k];
        if (j >= NN) j = 0;   // safety clamp
        if (tid < CIN) {
            float xj = xin[((size_t)(b * NN + j)) * CIN + tid];
            e[tid] = xi[tid];
            e[CIN + tid] = xj - xi[tid];
        }
        __syncthreads();
        if (tid < 64) {
            float v = 0.f;
            for (int c = 0; c < 2 * CIN; ++c) v += e[c] * b2f(w1s[c * 64 + tid]);
            h1[tid] = fmaxf(v + b1s[tid], 0.f);
        }
        __syncthreads();
        {
            float v = 0.f;
            for (int c = 0; c < 64; ++c) v += h1[c] * b2f(w2s[c * COUT + tid]);
            accmax = fmaxf(accmax, v + b2s[tid]);
        }
        __syncthreads();
    }
    if (BF16OUT) ((bf16*)out)[(size_t)bn * COUT + tid] = __float2bfloat16(accmax);
    else         ((float*)out)[(size_t)bn * COUT + tid] = accmax;
}

// ---------------------------------------------------------------- global max over N (2-stage)
__global__ __launch_bounds__(128) void gmax1_kernel(const bf16* __restrict__ f2,
                                                    float* __restrict__ pmax) {
    const int b = blockIdx.x >> 4, ch = blockIdx.x & 15, c = threadIdx.x;
    float m = -INFINITY;
    const bf16* base = f2 + ((size_t)(b * NN + ch * 128)) * 128 + c;
    for (int n = 0; n < 128; ++n) m = fmaxf(m, b2f(base[(size_t)n * 128]));
    pmax[blockIdx.x * 128 + c] = m;
}

__global__ __launch_bounds__(128) void gmax2_kernel(const float* __restrict__ pmax,
                                                    float* __restrict__ glob) {
    const int b = blockIdx.x, c = threadIdx.x;
    float m = -INFINITY;
    for (int ch = 0; ch < 16; ++ch) m = fmaxf(m, pmax[(b * 16 + ch) * 128 + c]);
    glob[b * 128 + c] = m;
}

// ---------------------------------------------------------------- K_h, V_h for one head (4 rows/block)
__global__ __launch_bounds__(256) void kvh_kernel(const bf16* __restrict__ f2,
                                                  const float* __restrict__ qkv_w,
                                                  bf16* __restrict__ kk,
                                                  bf16* __restrict__ vv, int h) {
    const int bn0 = blockIdx.x * 4;
    const int tid = threadIdx.x;
    __shared__ float Ws[2][128][32];  // 32 KB: [K|V][c][d] for head h
    __shared__ float f2s[4][128];
    for (int p = tid; p < 2 * 128 * 32; p += 256) {
        int kv = p >> 12, c = (p >> 5) & 127, d = p & 31;
        Ws[kv][c][d] = qkv_w[c * 384 + 128 + kv * 128 + h * 32 + d];
    }
    for (int p = tid; p < 4 * 128; p += 256) {
        int rr = p >> 7, c = p & 127;
        f2s[rr][c] = b2f(f2[(size_t)(bn0 + rr) * 128 + c]);
    }
    __syncthreads();
    const int rr = tid >> 6, u = tid & 63, kv = u >> 5, d = u & 31;
    float acc = 0.f;
    for (int c = 0; c < 128; ++c) acc += f2s[rr][c] * Ws[kv][c][d];
    bf16* dst = kv ? vv : kk;
    dst[(size_t)(bn0 + rr) * 32 + d] = __float2bfloat16(acc);
}

// ---------------------------------------------------------------- attention, one head (exact 2-pass softmax)
__global__ __launch_bounds__(256) void attnh_kernel(const bf16* __restrict__ f2,
                                                    const float* __restrict__ qkv_w,
                                                    const bf16* __restrict__ kk,
                                                    const bf16* __restrict__ vv,
                                                    bf16* __restrict__ atth, int h) {
    const int blk = blockIdx.x;            // B*32 = 256
    const int tile = blk & 31;
    const int b = blk >> 5;
    const int tid = threadIdx.x;
    const int r = tid & 63;
    const int sp = tid >> 6;
    const int i = tile * 64 + r;
    const float scale = 0.17677669529663687f;  // 32^-0.5
    __shared__ float WqS[128 * 32];        // 16 KB
    __shared__ float mred[4][64], lred[4][64];
    __shared__ float accs[4][64][32];      // 32 KB

    for (int p = tid; p < 4096; p += 256) {
        int c = p >> 5, d = p & 31;
        WqS[p] = qkv_w[c * 384 + h * 32 + d];
    }
    __syncthreads();

    float q[32];
    #pragma unroll
    for (int d = 0; d < 32; ++d) q[d] = 0.f;
    const bf16* frow = f2 + (size_t)(b * NN + i) * 128;
    for (int c = 0; c < 128; ++c) {
        float fv = b2f(frow[c]);
        const float* wrow = &WqS[c * 32];
        #pragma unroll
        for (int d = 0; d < 32; ++d) q[d] += fv * wrow[d];
    }

    const bf16* kb = kk + (size_t)b * NN * 32;
    const bf16* vb = vv + (size_t)b * NN * 32;
    const int j0 = sp * 512, j1 = j0 + 512;

    float m = -INFINITY;
    for (int j = j0; j < j1; ++j) {
        const bf16* kr = kb + (size_t)j * 32;
        float dsum = 0.f;
        #pragma unroll
        for (int d = 0; d < 32; ++d) dsum += q[d] * b2f(kr[d]);
        m = fmaxf(m, dsum * scale);
    }
    mred[sp][r] = m;
    __syncthreads();
    m = fmaxf(fmaxf(mred[0][r], mred[1][r]), fmaxf(mred[2][r], mred[3][r]));

    float l = 0.f;
    float a[32];
    #pragma unroll
    for (int d = 0; d < 32; ++d) a[d] = 0.f;
    for (int j = j0; j < j1; ++j) {
        const bf16* kr = kb + (size_t)j * 32;
        float dsum = 0.f;
        #pragma unroll
        for (int d = 0; d < 32; ++d) dsum += q[d] * b2f(kr[d]);
        float p = expf(dsum * scale - m);
        l += p;
        const bf16* vr = vb + (size_t)j * 32;
        #pragma unroll
        for (int d = 0; d < 32; ++d) a[d] += p * b2f(vr[d]);
    }
    lred[sp][r] = l;
    #pragma unroll
    for (int d = 0; d < 32; ++d) accs[sp][r][d] = a[d];
    __syncthreads();

    const int row = tid >> 2;
    const int dbase = (tid & 3) * 8;
    const float denom = lred[0][row] + lred[1][row] + lred[2][row] + lred[3][row];
    bf16* orow = atth + (size_t)(b * NN + tile * 64 + row) * 128 + h * 32;
    #pragma unroll
    for (int uu = 0; uu < 8; ++uu) {
        int d = dbase + uu;
        float v = accs[0][row][d] + accs[1][row][d] + accs[2][row][d] + accs[3][row][d];
        orow[d] = __float2bfloat16(v / denom);
    }
}

// ---------------------------------------------------------------- fused out-proj + concat + refine MLP + log_softmax
__global__ __launch_bounds__(128) void final_kernel(
        const bf16* __restrict__ f2, const float* __restrict__ glob,
        const bf16* __restrict__ atth,
        const float* __restrict__ out_w, const float* __restrict__ out_b,
        const float* __restrict__ r1_w, const float* __restrict__ r1_b,
        const float* __restrict__ r2_w, const float* __restrict__ r2_b,
        const float* __restrict__ r3_w, const float* __restrict__ r3_b,
        float* __restrict__ out) {
    const int bn0 = blockIdx.x * 4;
    const int b = bn0 >> 11;
    const int tid = threadIdx.x;
    __shared__ float attin[4][128], comb[4][384], h1[4][128], h2[4][64];
    __shared__ float logits[4][20], lse[4];

    #pragma unroll
    for (int rr = 0; rr < 4; ++rr) {
        attin[rr][tid]      = b2f(atth[(size_t)(bn0 + rr) * 128 + tid]);
        comb[rr][tid]       = b2f(f2[(size_t)(bn0 + rr) * 128 + tid]);
        comb[rr][128 + tid] = glob[b * 128 + tid];
    }
    __syncthreads();
    {
        float a0 = 0.f, a1 = 0.f, a2 = 0.f, a3 = 0.f;
        for (int c = 0; c < 128; ++c) {
            float wv = out_w[c * 128 + tid];
            a0 += attin[0][c] * wv; a1 += attin[1][c] * wv;
            a2 += attin[2][c] * wv; a3 += attin[3][c] * wv;
        }
        float bb = out_b[tid];
        comb[0][256 + tid] = a0 + bb; comb[1][256 + tid] = a1 + bb;
        comb[2][256 + tid] = a2 + bb; comb[3][256 + tid] = a3 + bb;
    }
    __syncthreads();
    {
        float a0 = 0.f, a1 = 0.f, a2 = 0.f, a3 = 0.f;
        for (int c = 0; c < 384; ++c) {
            float wv = r1_w[c * 128 + tid];
            a0 += comb[0][c] * wv; a1 += comb[1][c] * wv;
            a2 += comb[2][c] * wv; a3 += comb[3][c] * wv;
        }
        float bb = r1_b[tid];
        h1[0][tid] = fmaxf(a0 + bb, 0.f); h1[1][tid] = fmaxf(a1 + bb, 0.f);
        h1[2][tid] = fmaxf(a2 + bb, 0.f); h1[3][tid] = fmaxf(a3 + bb, 0.f);
    }
    __syncthreads();
    if (tid < 64) {
        float a0 = 0.f, a1 = 0.f, a2 = 0.f, a3 = 0.f;
        for (int c = 0; c < 128; ++c) {
            float wv = r2_w[c * 64 + tid];
            a0 += h1[0][c] * wv; a1 += h1[1][c] * wv;
            a2 += h1[2][c] * wv; a3 += h1[3][c] * wv;
        }
        float bb = r2_b[tid];
        h2[0][tid] = fmaxf(a0 + bb, 0.f); h2[1][tid] = fmaxf(a1 + bb, 0.f);
        h2[2][tid] = fmaxf(a2 + bb, 0.f); h2[3][tid] = fmaxf(a3 + bb, 0.f);
    }
    __syncthreads();
    if (tid < 20) {
        float a0 = 0.f, a1 = 0.f, a2 = 0.f, a3 = 0.f;
        for (int c = 0; c < 64; ++c) {
            float wv = r3_w[c * 20 + tid];
            a0 += h2[0][c] * wv; a1 += h2[1][c] * wv;
            a2 += h2[2][c] * wv; a3 += h2[3][c] * wv;
        }
        float bb = r3_b[tid];
        logits[0][tid] = a0 + bb; logits[1][tid] = a1 + bb;
        logits[2][tid] = a2 + bb; logits[3][tid] = a3 + bb;
    }
    __syncthreads();
    if (tid < 4) {
        float m = -INFINITY;
        for (int u = 0; u < 20; ++u) m = fmaxf(m, logits[tid][u]);
        float s = 0.f;
        for (int u = 0; u < 20; ++u) s += expf(logits[tid][u] - m);
        lse[tid] = m + logf(s);
    }
    __syncthreads();
    if (tid < 80) {
        int rr = tid / 20, cls = tid % 20;
        out[(size_t)(bn0 + rr) * 20 + cls] = logits[rr][cls] - lse[rr];
    }
}

// ----------------------------------------------------------------------------
// Workspace layout — NEED = 10,555,392 B (proven to fit in round 5):
//   [0,        4 MB)  phase 1-3: f1T fp32 (4 MB, knn2 reads)  -> phase 3+: f2 bf16
//   [4 MB,    10 MB)  shared slot:
//     phase 1-2:  sqb fp32 @4M (64 KB) | f1 fp32 @4M+64K (4 MB) |
//                 knn u16 @8M+64K (640 KB) | xT3 fp32 @~8.69M (192 KB)
//     phase 4:    kk bf16 @4M (1 MB) | vv bf16 @5M (1 MB) | atth bf16 @6M (4 MB)
//   [10 MB, +68 KB)   pmax fp32 | glob fp32
extern "C" void kernel_launch(void* const* d_in, const int* in_sizes, int n_in,
                              void* d_out, int out_size, void* d_ws, size_t ws_size,
                              hipStream_t stream) {
    const float* x      = (const float*)d_in[0];
    const float* ec1_w1 = (const float*)d_in[2];
    const float* ec1_b1 = (const float*)d_in[3];
    const float* ec1_w2 = (const float*)d_in[4];
    const float* ec1_b2 = (const float*)d_in[5];
    const float* ec2_w1 = (const float*)d_in[6];
    const float* ec2_b1 = (const float*)d_in[7];
    const float* ec2_w2 = (const float*)d_in[8];
    const float* ec2_b2 = (const float*)d_in[9];
    const float* qkv_w  = (const float*)d_in[10];
    const float* out_w  = (const float*)d_in[11];
    const float* out_b  = (const float*)d_in[12];
    const float* r1_w   = (const float*)d_in[13];
    const float* r1_b   = (const float*)d_in[14];
    const float* r2_w   = (const float*)d_in[15];
    const float* r2_b   = (const float*)d_in[16];
    const float* r3_w   = (const float*)d_in[17];
    const float* r3_b   = (const float*)d_in[18];
    float* out = (float*)d_out;

    const size_t NEED = 10555392;
    if (ws_size < NEED) return;   // guard: clean numeric fail instead of GPU fault

    char* base = (char*)d_ws;
    const size_t MB = 1024 * 1024;
    bf16*  f2   = (bf16*)(base);                      // phase 3+
    float* f1T  = (float*)(base);                     // phase 1-3 (dead before f2 written)
    float* sqb  = (float*)(base + 4 * MB);
    float* f1   = (float*)(base + 4 * MB + 65536);
    u16*   knn  = (u16*)(base + 8 * MB + 65536);      // 640 KB
    float* xT3  = (float*)(base + 8 * MB + 65536 + 655360);  // 192 KB, ends < 9.3 MB
    bf16*  kk   = (bf16*)(base + 4 * MB);             // phase-4 slot reuse
    bf16*  vv   = (bf16*)(base + 5 * MB);
    bf16*  atth = (bf16*)(base + 6 * MB);
    float* pmax = (float*)(base + 10 * MB);
    float* glob = (float*)(base + 10 * MB + 65536);

    sqT_kernel<3><<<BBNN / 256, 256, 0, stream>>>(x, sqb, xT3);
    knn_fast_kernel<3><<<BB * 256, 512, 0, stream>>>(x, xT3, sqb, knn);
    edgeconv_kernel<3, 64, false><<<BB * NN, 64, 0, stream>>>(
        x, knn, ec1_w1, ec1_b1, ec1_w2, ec1_b2, f1);

    sqT_kernel<64><<<BBNN / 256, 256, 0, stream>>>(f1, sqb, f1T);
    knn_fast_kernel<64><<<BB * 256, 512, 0, stream>>>(f1, f1T, sqb, knn);
    edgeconv_kernel<64, 128, true><<<BB * NN, 128, 0, stream>>>(
        f1, knn, ec2_w1, ec2_b1, ec2_w2, ec2_b2, f2);

    gmax1_kernel<<<BB * 16, 128, 0, stream>>>(f2, pmax);
    gmax2_kernel<<<BB, 128, 0, stream>>>(pmax, glob);

    for (int h = 0; h < 4; ++h) {
        kvh_kernel<<<BB * NN / 4, 256, 0, stream>>>(f2, qkv_w, kk, vv, h);
        attnh_kernel<<<BB * 32, 256, 0, stream>>>(f2, qkv_w, kk, vv, atth, h);
    }

    final_kernel<<<BB * NN / 4, 128, 0, stream>>>(
        f2, glob, atth, out_w, out_b, r1_w, r1_b, r2_w, r2_b, r3_w, r3_b, out);
}